// Round 2
// baseline (643.169 us; speedup 1.0000x reference)
//
#include <hip/hip_runtime.h>

// Problem constants
constexpr int Bn   = 32;
constexpr int CIN  = 64;
constexpr int Lx   = 8192;
constexpr int L1   = 8190;   // length after kw=3,d=1 VALID conv
constexpr int LOUT = 8186;   // final output length
constexpr int NCH  = 384;

// workspace layout (float offsets)
constexpr int WS1_OFF = 0;      // 64*64 transposed stage-1 weights
constexpr int H_OFF   = 4096;
constexpr int HSTR    = 8208;   // per-(b,ch) row stride; element i <-> u = i-8
// h rows: ch 0-5 = h7 (post stage-1 branch7), 6-11 = h10b, 12-17 = h15b

// ---------------- prep: transpose stage-1 weights ----------------
// ws[ci*64 + k*3 + j]; k 0..5 w7_1, 6..11 w10_1, 12..17 w15_1
__global__ void prep_weights(const float* __restrict__ w7_1,
                             const float* __restrict__ w10_1,
                             const float* __restrict__ w15_1,
                             float* __restrict__ ws) {
    int idx = blockIdx.x * blockDim.x + threadIdx.x;
    if (idx >= 64 * 54) return;
    int ci = idx / 54, r = idx % 54;
    int k = r / 3, j = r % 3;
    const float* src = (k < 6) ? w7_1 : ((k < 12) ? w10_1 : w15_1);
    int kk = (k < 6) ? k : ((k < 12) ? k - 6 : k - 12);
    ws[WS1_OFF + ci * 64 + r] = src[kk * 192 + ci * 3 + j];
}

// ---------------- kernel A: stage 1 (64->18) + stage 2 (6->6 x2) ----------
constexpr int TTA = 252;                      // 252 outputs + 4 halo = 256 work items
constexpr int NTA = (L1 + TTA - 1) / TTA;     // 33

__global__ __launch_bounds__(256)
void stage12(const float* __restrict__ x, float* __restrict__ ws,
             const float* __restrict__ w10_3, const float* __restrict__ w15_3) {
    __shared__ float a2[12][256];
    const int tid = threadIdx.x;
    const int t0  = blockIdx.x * TTA;
    const int b   = blockIdx.y;
    const float* xb = x + (size_t)b * CIN * Lx;
    float* hb = ws + H_OFF + (size_t)b * 18 * HSTR;

    // zero the 8 causal-pad lead elements of every row (once per b)
    if (blockIdx.x == 0 && tid < 18 * 8)
        hb[(tid >> 3) * HSTR + (tid & 7)] = 0.f;

    const int s = t0 + tid;                    // stage-1 output position
    float acc[18];
    #pragma unroll
    for (int k = 0; k < 18; ++k) acc[k] = 0.f;
    if (s < L1) {
        const float* xr = xb + s;
        const float* w0 = ws + WS1_OFF;
        for (int ci = 0; ci < CIN; ++ci) {
            const float x0 = xr[0];
            const float x1 = xr[1];
            const float x2 = xr[2];
            const float* wr = w0 + ci * 64;    // uniform -> s_load
            #pragma unroll
            for (int k = 0; k < 18; ++k) {
                acc[k] = fmaf(wr[k * 3 + 0], x0, acc[k]);
                acc[k] = fmaf(wr[k * 3 + 1], x1, acc[k]);
                acc[k] = fmaf(wr[k * 3 + 2], x2, acc[k]);
            }
            xr += Lx;
        }
        #pragma unroll
        for (int k = 0; k < 18; ++k) acc[k] = fmaxf(acc[k], 0.f);
        // branch-7 stage-1 output goes straight to global h rows 0..5
        if (tid < TTA) {
            #pragma unroll
            for (int c = 0; c < 6; ++c) hb[c * HSTR + 8 + s] = acc[c];
        }
    }
    #pragma unroll
    for (int c = 0; c < 12; ++c) a2[c][tid] = acc[6 + c];
    __syncthreads();

    // stage 2: kw=3, d=2, 6->6 for branches 10 and 15
    const int u = t0 + tid;
    if (tid < TTA && u < LOUT) {
        float v[18];
        #pragma unroll
        for (int c = 0; c < 6; ++c)
            #pragma unroll
            for (int j = 0; j < 3; ++j) v[c * 3 + j] = a2[c][tid + 2 * j];
        #pragma unroll
        for (int k = 0; k < 6; ++k) {
            float a = 0.f;
            #pragma unroll
            for (int r = 0; r < 18; ++r) a = fmaf(w10_3[k * 18 + r], v[r], a);
            hb[(6 + k) * HSTR + 8 + u] = fmaxf(a, 0.f);
        }
        #pragma unroll
        for (int c = 0; c < 6; ++c)
            #pragma unroll
            for (int j = 0; j < 3; ++j) v[c * 3 + j] = a2[6 + c][tid + 2 * j];
        #pragma unroll
        for (int k = 0; k < 6; ++k) {
            float a = 0.f;
            #pragma unroll
            for (int r = 0; r < 18; ++r) a = fmaf(w15_3[k * 18 + r], v[r], a);
            hb[(12 + k) * HSTR + 8 + u] = fmaxf(a, 0.f);
        }
    }
}

// ---------------- kernel B: stage 3 (6->128 per branch) + relu + store ----
constexpr int TTB = 512;
constexpr int NTB = 16;   // 16*512 = 8192 >= 8186

__device__ __forceinline__ void store8(float* __restrict__ op, int t,
                                       float* __restrict__ a) {
    #pragma unroll
    for (int d = 0; d < 8; ++d) a[d] = fmaxf(a[d], 0.f);
    if (t + 7 < LOUT) {
        #pragma unroll
        for (int d = 0; d < 8; d += 2)
            *(float2*)(op + t + d) = make_float2(a[d], a[d + 1]);   // rows 8B-aligned
    } else {
        #pragma unroll
        for (int d = 0; d < 8; ++d)
            if (t + d < LOUT) op[t + d] = a[d];
    }
}

__global__ __launch_bounds__(256)
void stage3(const float* __restrict__ ws,
            const float* __restrict__ w7_3,
            const float* __restrict__ w10_5,
            const float* __restrict__ w15_5,
            float* __restrict__ out) {
    __shared__ float hs[6][528];               // i in [t0, t0+528)
    const int tid = threadIdx.x;
    const int t0  = blockIdx.x * TTB;
    const int br  = blockIdx.y;                // 0: branch7, 1: branch10, 2: branch15
    const int b   = blockIdx.z;
    const float* hb = ws + H_OFF + ((size_t)b * 18 + br * 6) * HSTR;

    // cooperative LDS load: 6 rows x 528 floats, 16B-aligned float4s
    for (int idx = tid; idx < 6 * 132; idx += 256) {
        const int c = idx / 132, q = idx - c * 132;
        *(float4*)&hs[c][q * 4] = *(const float4*)&hb[c * HSTR + t0 + q * 4];
    }
    __syncthreads();

    const int tq  = tid & 63;                  // lane owns 8 consecutive t
    const int wvU = __builtin_amdgcn_readfirstlane(threadIdx.x >> 6); // wave-uniform!
    const int t   = t0 + tq * 8;
    const int rel = tq * 8;                    // LDS window base (i - t0)

    if (br == 0) {
        // kw=3, d=2: out[t+d] = sum_c,j w[c*3+j] * h7[t+d+2j]; i = u+8
        float v[6][12];
        #pragma unroll
        for (int c = 0; c < 6; ++c)
            #pragma unroll
            for (int m = 0; m < 12; m += 4)
                *(float4*)&v[c][m] = *(const float4*)&hs[c][rel + 8 + m];
        const float* wb = w7_3 + wvU * 32 * 18;
        float* ob = out + ((size_t)b * NCH + wvU * 32) * LOUT;
        #pragma unroll 2
        for (int oi = 0; oi < 32; ++oi) {
            const float* wr = wb + oi * 18;    // wave-uniform -> s_load
            float a[8];
            #pragma unroll
            for (int d = 0; d < 8; ++d) a[d] = 0.f;
            #pragma unroll
            for (int c = 0; c < 6; ++c)
                #pragma unroll
                for (int j = 0; j < 3; ++j) {
                    const float w = wr[c * 3 + j];
                    #pragma unroll
                    for (int d = 0; d < 8; ++d) a[d] = fmaf(w, v[c][d + 2 * j], a[d]);
                }
            store8(ob + (size_t)oi * LOUT, t, a);
        }
    } else if (br == 1) {
        // kw=2, d=4, causal pad 4: out[t+d] = sum_c,j w[c*2+j] * h10b[t+d-4+4j]
        float v[6][12];
        #pragma unroll
        for (int c = 0; c < 6; ++c)
            #pragma unroll
            for (int m = 0; m < 12; m += 4)
                *(float4*)&v[c][m] = *(const float4*)&hs[c][rel + 4 + m];
        const float* wb = w10_5 + wvU * 32 * 12;
        float* ob = out + ((size_t)b * NCH + 128 + wvU * 32) * LOUT;
        #pragma unroll 2
        for (int oi = 0; oi < 32; ++oi) {
            const float* wr = wb + oi * 12;
            float a[8];
            #pragma unroll
            for (int d = 0; d < 8; ++d) a[d] = 0.f;
            #pragma unroll
            for (int c = 0; c < 6; ++c) {
                const float w0 = wr[c * 2 + 0];
                const float w1 = wr[c * 2 + 1];
                #pragma unroll
                for (int d = 0; d < 8; ++d) {
                    a[d] = fmaf(w0, v[c][d], a[d]);
                    a[d] = fmaf(w1, v[c][d + 4], a[d]);
                }
            }
            store8(ob + (size_t)oi * LOUT, t, a);
        }
    } else {
        // kw=3, d=4, causal pad 8: out[t+d] = sum_c,j w[c*3+j] * h15b[t+d-8+4j]
        float v[6][16];
        #pragma unroll
        for (int c = 0; c < 6; ++c)
            #pragma unroll
            for (int m = 0; m < 16; m += 4)
                *(float4*)&v[c][m] = *(const float4*)&hs[c][rel + m];
        const float* wb = w15_5 + wvU * 32 * 18;
        float* ob = out + ((size_t)b * NCH + 256 + wvU * 32) * LOUT;
        #pragma unroll 2
        for (int oi = 0; oi < 32; ++oi) {
            const float* wr = wb + oi * 18;
            float a[8];
            #pragma unroll
            for (int d = 0; d < 8; ++d) a[d] = 0.f;
            #pragma unroll
            for (int c = 0; c < 6; ++c)
                #pragma unroll
                for (int j = 0; j < 3; ++j) {
                    const float w = wr[c * 3 + j];
                    #pragma unroll
                    for (int d = 0; d < 8; ++d) a[d] = fmaf(w, v[c][d + 4 * j], a[d]);
                }
            store8(ob + (size_t)oi * LOUT, t, a);
        }
    }
}

extern "C" void kernel_launch(void* const* d_in, const int* in_sizes, int n_in,
                              void* d_out, int out_size, void* d_ws, size_t ws_size,
                              hipStream_t stream) {
    const float* x     = (const float*)d_in[0];
    const float* w7_1  = (const float*)d_in[1];
    const float* w7_3  = (const float*)d_in[2];
    const float* w10_1 = (const float*)d_in[3];
    const float* w10_3 = (const float*)d_in[4];
    const float* w10_5 = (const float*)d_in[5];
    const float* w15_1 = (const float*)d_in[6];
    const float* w15_3 = (const float*)d_in[7];
    const float* w15_5 = (const float*)d_in[8];
    float* out = (float*)d_out;
    float* ws  = (float*)d_ws;   // needs (4096 + 32*18*8208)*4 ~= 18.9 MB

    prep_weights<<<dim3(14), dim3(256), 0, stream>>>(w7_1, w10_1, w15_1, ws);
    stage12<<<dim3(NTA, Bn), dim3(256), 0, stream>>>(x, ws, w10_3, w15_3);
    stage3<<<dim3(NTB, 3, Bn), dim3(256), 0, stream>>>(ws, w7_3, w10_5, w15_5, out);
}